// Round 16
// baseline (229.506 us; speedup 1.0000x reference)
//
#include <hip/hip_runtime.h>

#define THREADS 256

__device__ __forceinline__ float sigmoidf(float x) {
    return __builtin_amdgcn_rcpf(1.0f + __expf(-x));
}

// ---------------------------------------------------------------------------
// ws layout (floats):
//   [0,168)        e1p : conv1 eff weights, padded [6][28]
//   [168,2856)     e2p : conv2 eff weights, padded [16][6][28]
//   [2856,50856)   e3c : conv3 eff weights, 2-CHANNEL-PER-THREAD layout:
//                        f4[(k*120 + t)*2 + j] = w_eff[2*(t>>1)+j][(t&1)*200+4k..]
//                        t in [0,120), k in [0,50), j in {0,1}. 48000 floats.
//   [54056, +n*1176)  p1 : conv1 pooled out [img][6][196]
//   [.., +n*400)      p2 : conv2 pooled out [img][400]
// ---------------------------------------------------------------------------
#define E2OFF 168
#define E3OFF 2856
#define P1OFF 54056

__global__ void weff_prep(const float* __restrict__ w1, const float* __restrict__ sg1, const int* __restrict__ sr1,
                          const float* __restrict__ w2, const float* __restrict__ sg2, const int* __restrict__ sr2,
                          const float* __restrict__ w3, const float* __restrict__ sg3, const int* __restrict__ sr3,
                          const int* __restrict__ trig, float* __restrict__ ws) {
    int i = blockIdx.x * blockDim.x + threadIdx.x;
    const int t = trig[0];
    if (i < 168) {
        int c = i / 28, k = i % 28;
        float v = 0.f;
        if (k < 25) { int f = c * 25 + k; v = t ? sg1[f] * w1[c * 25 + sr1[f]] : w1[f]; }
        ws[i] = v;
    } else if (i < E3OFF) {
        int j = i - E2OFF;
        int oc = j / 168, r = j % 168, ic = r / 28, k = r % 28;
        float v = 0.f;
        if (k < 25) { int f = oc * 150 + ic * 25 + k; v = t ? sg2[f] * w2[oc * 150 + sr2[f]] : w2[f]; }
        ws[i] = v;
    } else if (i < P1OFF) {
        // 2-channel-per-thread conv3 weights (see layout comment)
        int idx = i - E3OFF;              // 0..51199 (only [0,48000) used)
        if (idx < 48000) {
            int q  = idx & 3;
            int j  = (idx >> 2) & 1;
            int tt = (idx >> 3) % 120;
            int k  = idx / 960;
            int c  = 2 * (tt >> 1) + j;
            int h  = tt & 1;
            int e  = c * 400 + h * 200 + 4 * k + q;
            ws[i] = t ? sg3[e] * w3[c * 400 + sr3[e]] : w3[e];
        } else {
            ws[i] = 0.f;
        }
    }
}

// ---- conv1 (1->6, 5x5) + sigmoid + avgpool2 ----
// thread = (img, pooled row r, pooled col-pair t). Patch 6x8: 2 aligned
// float4 per row. Stores float2 dense. (256,4) is FINAL: R14's (256,6)
// forced VGPR 64->40 -> 379 MB spill. Do not touch the bound.
__global__ __launch_bounds__(THREADS, 4)
void k_conv1(const float* __restrict__ x, const float* __restrict__ ws,
             const float* __restrict__ b1, float* __restrict__ p1, int nimg) {
    __shared__ __align__(16) float lw[176];
    const int tid = threadIdx.x;
    if (tid < 168) lw[tid] = ws[tid];
    if (tid >= 168 && tid < 174) lw[tid] = b1[tid - 168];
    __syncthreads();

    int g = blockIdx.x * THREADS + tid;
    if (g >= nimg * 98) return;
    const int img = g / 98, rem = g % 98;
    const int r = rem / 7, t = rem % 7;

    const float* xb = x + (size_t)img * 1024 + (2 * r) * 32 + 4 * t;
    float pt[6][8];
    #pragma unroll
    for (int rr = 0; rr < 6; ++rr) {
        const float4 v0 = *reinterpret_cast<const float4*>(xb + rr * 32);
        const float4 v1 = *reinterpret_cast<const float4*>(xb + rr * 32 + 4);
        pt[rr][0] = v0.x; pt[rr][1] = v0.y; pt[rr][2] = v0.z; pt[rr][3] = v0.w;
        pt[rr][4] = v1.x; pt[rr][5] = v1.y; pt[rr][6] = v1.z; pt[rr][7] = v1.w;
    }

    #pragma unroll
    for (int c = 0; c < 6; ++c) {
        float z[2][4];
        #pragma unroll
        for (int p = 0; p < 2; ++p)
            #pragma unroll
            for (int w = 0; w < 4; ++w) z[p][w] = 0.f;

        #pragma unroll
        for (int k4 = 0; k4 < 6; ++k4) {
            const float4 w4 = *reinterpret_cast<const float4*>(&lw[c * 28 + 4 * k4]);
            #pragma unroll
            for (int j = 0; j < 4; ++j) {
                const int k = 4 * k4 + j;
                const int ky = k / 5, kx = k % 5;
                const float wv = (j == 0) ? w4.x : (j == 1) ? w4.y : (j == 2) ? w4.z : w4.w;
                #pragma unroll
                for (int p = 0; p < 2; ++p)
                    #pragma unroll
                    for (int dy = 0; dy < 2; ++dy)
                        #pragma unroll
                        for (int dx = 0; dx < 2; ++dx)
                            z[p][2 * dy + dx] += pt[dy + ky][2 * p + dx + kx] * wv;
            }
        }
        { // k = 24 (ky=4, kx=4)
            const float wv = lw[c * 28 + 24];
            #pragma unroll
            for (int p = 0; p < 2; ++p)
                #pragma unroll
                for (int dy = 0; dy < 2; ++dy)
                    #pragma unroll
                    for (int dx = 0; dx < 2; ++dx)
                        z[p][2 * dy + dx] += pt[dy + 4][2 * p + dx + 4] * wv;
        }

        const float bb = lw[168 + c];
        const float s0 = sigmoidf(z[0][0] + bb) + sigmoidf(z[0][1] + bb) +
                         sigmoidf(z[0][2] + bb) + sigmoidf(z[0][3] + bb);
        const float s1 = sigmoidf(z[1][0] + bb) + sigmoidf(z[1][1] + bb) +
                         sigmoidf(z[1][2] + bb) + sigmoidf(z[1][3] + bb);
        *reinterpret_cast<float2*>(&p1[((size_t)img * 6 + c) * 196 + r * 14 + 2 * t]) =
            make_float2(0.25f * s0, 0.25f * s1);
    }
}

// ---- conv2 (6->16, 5x5) + sigmoid + avgpool2 -- window-split ----
// thread = (img, pooled pixel, pool-row di); weights loop-uniform -> s_load.
// (256,4): R15 body uses only 48 VGPR (< the 64-VGPR level that supports up
// to 8 waves/SIMD). R8/R9's spill trap was ~90-reg bodies under a 64 cap --
// not this. Occupancy 46% -> ~60% for patch/s_load latency hiding.
// Tripwire: VGPR < 48 or WRITE > 100 MB -> revert to (256,3).
__global__ __launch_bounds__(THREADS, 4)
void k_conv2(const float* __restrict__ p1, const float* __restrict__ ws,
             const float* __restrict__ b2, float* __restrict__ p2, int nimg) {
    int g = blockIdx.x * THREADS + threadIdx.x;
    if (g >= nimg * 50) return;
    const int img = g / 50, rem = g % 50;
    const int pix = rem >> 1, di = rem & 1;
    const int pi = pix / 5, pj = pix % 5;
    const float* pimg = p1 + (size_t)img * 1176 + (2 * pi + di) * 14 + 2 * pj;
    const float* wq = ws + E2OFF;

    float acc[16][2];
    #pragma unroll
    for (int oc = 0; oc < 16; ++oc) { acc[oc][0] = 0.f; acc[oc][1] = 0.f; }

    #pragma unroll 2
    for (int ic = 0; ic < 6; ++ic) {
        float pt[5][6];
        const float* pb = pimg + ic * 196;
        #pragma unroll
        for (int r = 0; r < 5; ++r) {
            #pragma unroll
            for (int cc = 0; cc < 3; ++cc) {
                float2 v = *reinterpret_cast<const float2*>(pb + r * 14 + 2 * cc);
                pt[r][2 * cc] = v.x; pt[r][2 * cc + 1] = v.y;
            }
        }
        #pragma unroll
        for (int oc = 0; oc < 16; ++oc) {
            const float* wr = wq + oc * 168 + ic * 28;   // uniform (loop vars)
            #pragma unroll
            for (int k4 = 0; k4 < 6; ++k4) {
                const float4 w4 = *reinterpret_cast<const float4*>(wr + 4 * k4);
                #pragma unroll
                for (int j = 0; j < 4; ++j) {
                    const int k = 4 * k4 + j;
                    const int ky = k / 5, kx = k % 5;
                    const float wv = (j == 0) ? w4.x : (j == 1) ? w4.y : (j == 2) ? w4.z : w4.w;
                    acc[oc][0] += pt[ky][kx] * wv;
                    acc[oc][1] += pt[ky][kx + 1] * wv;
                }
            }
            const float wv = wr[24];
            acc[oc][0] += pt[4][4] * wv;
            acc[oc][1] += pt[4][5] * wv;
        }
    }

    #pragma unroll
    for (int oc = 0; oc < 16; ++oc) {
        const float bb = b2[oc];
        float s = sigmoidf(acc[oc][0] + bb) + sigmoidf(acc[oc][1] + bb);
        s += __shfl_xor(s, 1, 64);     // combine di=0 / di=1 (adjacent lanes)
        if (di == 0)
            p2[(size_t)img * 400 + oc * 25 + pix] = 0.25f * s;
    }
}

// ---- conv3 (16->120) + sigmoid, fc1 + sigmoid, fc2 -- 2 ch/thread ----
// Thread t=(cpair,h) owns channels 2*cpair, 2*cpair+1: each u ds_read feeds
// 8 FMAs -> 800 wave ds_reads/block (~32us LDS-pipe). Weights via e3c:
// 32 B/lane contiguous, 2 KB/wave dense. h-partners adjacent ->
// __shfl_xor(s,1). acc[2][8] scalars ~75 VGPR < (128,4)'s cap.
#define T_IMG 8
__global__ __launch_bounds__(128, 4)
void k_tail(const float* __restrict__ p2, const float* __restrict__ ws,
            const float* __restrict__ b3,
            const float* __restrict__ fc1w, const float* __restrict__ fc1b,
            const float* __restrict__ fc2w, const float* __restrict__ fc2b,
            float* __restrict__ out, int nimg) {
    __shared__ __align__(16) float sp2[T_IMG][400];
    __shared__ __align__(16) float v3[T_IMG][120];
    __shared__ __align__(16) float v4[T_IMG][84];
    const int tid = threadIdx.x;
    const int img0 = blockIdx.x * T_IMG;

    for (int i = tid; i < T_IMG * 100; i += 128) {
        const int im = i / 100, off = i % 100;
        const int gi = min(img0 + im, nimg - 1);
        reinterpret_cast<float4*>(&sp2[im][0])[off] =
            reinterpret_cast<const float4*>(p2 + (size_t)gi * 400)[off];
    }
    __syncthreads();

    if (tid < 120) {
        const int h = tid & 1;
        const int cpair = tid >> 1;
        float acc[2][T_IMG];
        #pragma unroll
        for (int j = 0; j < 2; ++j)
            #pragma unroll
            for (int im = 0; im < T_IMG; ++im) acc[j][im] = 0.f;

        const float4* wp = reinterpret_cast<const float4*>(ws + E3OFF);
        #pragma unroll 2
        for (int k = 0; k < 50; ++k) {
            const float4 w0 = wp[(k * 120 + tid) * 2];
            const float4 w1 = wp[(k * 120 + tid) * 2 + 1];
            #pragma unroll
            for (int im = 0; im < T_IMG; ++im) {
                const float4 u = *reinterpret_cast<const float4*>(&sp2[im][h * 200 + 4 * k]);
                acc[0][im] += w0.x * u.x + w0.y * u.y + w0.z * u.z + w0.w * u.w;
                acc[1][im] += w1.x * u.x + w1.y * u.y + w1.z * u.z + w1.w * u.w;
            }
        }
        #pragma unroll
        for (int j = 0; j < 2; ++j) {
            const int c = 2 * cpair + j;
            const float bb = b3[c];
            #pragma unroll
            for (int im = 0; im < T_IMG; ++im) {
                float s = acc[j][im];
                s += __shfl_xor(s, 1, 64);   // combine h=0/h=1 (adjacent lanes)
                if (h == 0) v3[im][c] = sigmoidf(s + bb);
            }
        }
    }
    __syncthreads();

    for (int it = tid; it < T_IMG * 84; it += 128) {
        const int im = it / 84, j = it % 84;
        const float4* wp = reinterpret_cast<const float4*>(fc1w + j * 120);
        const float4* vp = reinterpret_cast<const float4*>(&v3[im][0]);
        float4 a = make_float4(0.f, 0.f, 0.f, 0.f);
        #pragma unroll 6
        for (int k = 0; k < 30; ++k) {
            const float4 w4 = wp[k];
            const float4 u = vp[k];
            a.x += u.x * w4.x; a.y += u.y * w4.y;
            a.z += u.z * w4.z; a.w += u.w * w4.w;
        }
        v4[im][j] = sigmoidf((a.x + a.y) + (a.z + a.w) + fc1b[j]);
    }
    __syncthreads();

    if (tid < T_IMG * 10) {
        const int im = tid / 10, j = tid % 10;
        if (img0 + im < nimg) {
            const float4* wp = reinterpret_cast<const float4*>(fc2w + j * 84);
            const float4* vp = reinterpret_cast<const float4*>(&v4[im][0]);
            float4 a = make_float4(0.f, 0.f, 0.f, 0.f);
            #pragma unroll
            for (int k = 0; k < 21; ++k) {
                const float4 w4 = wp[k];
                const float4 u = vp[k];
                a.x += u.x * w4.x; a.y += u.y * w4.y;
                a.z += u.z * w4.z; a.w += u.w * w4.w;
            }
            out[(size_t)(img0 + im) * 10 + j] = (a.x + a.y) + (a.z + a.w) + fc2b[j];
        }
    }
}

// ---------------- fallback: single fused kernel, inline gather ----------------
__device__ __forceinline__ float wget_ig(const float* __restrict__ wp,
                                         const float* __restrict__ sg,
                                         const int* __restrict__ sr,
                                         int row, int m, int idx, bool tg) {
    int f = row * m + idx;
    return tg ? sg[f] * wp[row * m + sr[f]] : wp[f];
}

__global__ __launch_bounds__(THREADS, 4)
void lenet_fused(const float* __restrict__ x,
                 const float* __restrict__ w1e, const float* __restrict__ b1,
                 const float* __restrict__ w2e, const float* __restrict__ b2,
                 const float* __restrict__ w3e, const float* __restrict__ b3,
                 const float* __restrict__ fc1w, const float* __restrict__ fc1b,
                 const float* __restrict__ fc2w, const float* __restrict__ fc2b,
                 const float* __restrict__ sg1, const int* __restrict__ sr1,
                 const float* __restrict__ sg2, const int* __restrict__ sr2,
                 const float* __restrict__ sg3, const int* __restrict__ sr3,
                 const int* __restrict__ trig,
                 float* __restrict__ out, int nimg) {
    const int tid = threadIdx.x;
    const int img0 = blockIdx.x * 2;
    __shared__ __align__(16) float xs[2][1024];
    __shared__ __align__(16) float p1[2][6][196];
    __shared__ __align__(16) float p2[2][400];
    __shared__ __align__(16) float v3[2][120];
    __shared__ __align__(16) float v4[2][84];
    const bool tg = trig[0] != 0;

    #pragma unroll
    for (int im = 0; im < 2; ++im) {
        int gi = min(img0 + im, nimg - 1);
        reinterpret_cast<float4*>(&xs[im][0])[tid] =
            reinterpret_cast<const float4*>(x + (size_t)gi * 1024)[tid];
    }
    __syncthreads();

    for (int it = tid; it < 2 * 196; it += THREADS) {
        const int img = it / 196, pix = it % 196;
        const int pi = pix / 14, pj = pix % 14;
        const float* xb = &xs[img][(2 * pi) * 32 + 2 * pj];
        float pt[6][6];
        #pragma unroll
        for (int r = 0; r < 6; ++r)
            #pragma unroll
            for (int cc = 0; cc < 3; ++cc) {
                float2 v = *reinterpret_cast<const float2*>(&xb[r * 32 + cc * 2]);
                pt[r][cc * 2] = v.x; pt[r][cc * 2 + 1] = v.y;
            }
        #pragma unroll
        for (int c = 0; c < 6; ++c) {
            float z0 = 0.f, z1 = 0.f, z2 = 0.f, z3 = 0.f;
            #pragma unroll
            for (int ky = 0; ky < 5; ++ky)
                #pragma unroll
                for (int kx = 0; kx < 5; ++kx) {
                    const float wv = wget_ig(w1e, sg1, sr1, c, 25, ky * 5 + kx, tg);
                    z0 += pt[ky][kx] * wv;     z1 += pt[ky][kx + 1] * wv;
                    z2 += pt[ky + 1][kx] * wv; z3 += pt[ky + 1][kx + 1] * wv;
                }
            const float bb = b1[c];
            p1[img][c][pix] = 0.25f * (sigmoidf(z0 + bb) + sigmoidf(z1 + bb) +
                                       sigmoidf(z2 + bb) + sigmoidf(z3 + bb));
        }
    }
    __syncthreads();

    if (tid < 200) {
        const int img = tid / 100, rem = tid % 100;
        const int pix = rem >> 2, win = rem & 3;
        const int di = win >> 1, dj = win & 1;
        const int pi = pix / 5, pj = pix % 5;
        const int r0 = 2 * pi + di, c0 = 2 * pj + dj;
        float acc[16];
        #pragma unroll
        for (int c = 0; c < 16; ++c) acc[c] = 0.f;
        for (int ic = 0; ic < 6; ++ic) {
            float pt[5][5];
            #pragma unroll
            for (int ky = 0; ky < 5; ++ky)
                #pragma unroll
                for (int kx = 0; kx < 5; ++kx)
                    pt[ky][kx] = p1[img][ic][(r0 + ky) * 14 + (c0 + kx)];
            #pragma unroll
            for (int c = 0; c < 16; ++c) {
                float z = acc[c];
                #pragma unroll
                for (int ky = 0; ky < 5; ++ky)
                    #pragma unroll
                    for (int kx = 0; kx < 5; ++kx)
                        z += pt[ky][kx] * wget_ig(w2e, sg2, sr2, c, 150, ic * 25 + ky * 5 + kx, tg);
                acc[c] = z;
            }
        }
        #pragma unroll
        for (int c = 0; c < 16; ++c) {
            float z = sigmoidf(acc[c] + b2[c]);
            z += __shfl_xor(z, 1, 64);
            z += __shfl_xor(z, 2, 64);
            if (win == 0) p2[img][c * 25 + pix] = 0.25f * z;
        }
    }
    __syncthreads();

    if (tid < 240) {
        const int c = tid >> 1, h = tid & 1;
        float s0 = 0.f, s1 = 0.f;
        for (int k = 0; k < 200; ++k) {
            float wv = wget_ig(w3e, sg3, sr3, c, 400, h * 200 + k, tg);
            s0 += p2[0][h * 200 + k] * wv;
            s1 += p2[1][h * 200 + k] * wv;
        }
        s0 += __shfl_xor(s0, 1, 64);
        s1 += __shfl_xor(s1, 1, 64);
        if (h == 0) {
            const float bb = b3[c];
            v3[0][c] = sigmoidf(s0 + bb);
            v3[1][c] = sigmoidf(s1 + bb);
        }
    }
    __syncthreads();

    if (tid < 168) {
        const int img = tid / 84, j = tid % 84;
        float a = 0.f;
        for (int k = 0; k < 120; ++k) a += v3[img][k] * fc1w[j * 120 + k];
        v4[img][j] = sigmoidf(a + fc1b[j]);
    }
    __syncthreads();

    if (tid < 20) {
        const int img = tid / 10, j = tid % 10;
        if (img0 + img < nimg) {
            float a = 0.f;
            for (int k = 0; k < 84; ++k) a += v4[img][k] * fc2w[j * 84 + k];
            out[(size_t)(img0 + img) * 10 + j] = a + fc2b[j];
        }
    }
}

extern "C" void kernel_launch(void* const* d_in, const int* in_sizes, int n_in,
                              void* d_out, int out_size, void* d_ws, size_t ws_size,
                              hipStream_t stream) {
    const float* x    = (const float*)d_in[0];
    const float* w1   = (const float*)d_in[1];
    const float* b1   = (const float*)d_in[2];
    const float* sg1  = (const float*)d_in[3];
    const float* w2   = (const float*)d_in[4];
    const float* b2   = (const float*)d_in[5];
    const float* sg2  = (const float*)d_in[6];
    const float* w3   = (const float*)d_in[7];
    const float* b3   = (const float*)d_in[8];
    const float* sg3  = (const float*)d_in[9];
    const float* fc1w = (const float*)d_in[10];
    const float* fc1b = (const float*)d_in[11];
    const float* fc2w = (const float*)d_in[12];
    const float* fc2b = (const float*)d_in[13];
    const int*   sr1  = (const int*)d_in[14];
    const int*   sr2  = (const int*)d_in[15];
    const int*   sr3  = (const int*)d_in[16];
    const int*   trig = (const int*)d_in[17];

    const int nimg = in_sizes[0] / 1024;
    float* out = (float*)d_out;

    const size_t p1off = P1OFF;
    const size_t p2off = p1off + (size_t)nimg * 1176;
    const size_t need_bytes = (p2off + (size_t)nimg * 400) * sizeof(float);

    if (ws_size >= need_bytes) {
        float* ws = (float*)d_ws;
        weff_prep<<<(P1OFF + 255) / 256, 256, 0, stream>>>(
            w1, sg1, sr1, w2, sg2, sr2, w3, sg3, sr3, trig, ws);
        k_conv1<<<(nimg * 98 + THREADS - 1) / THREADS, THREADS, 0, stream>>>(
            x, ws, b1, ws + p1off, nimg);
        k_conv2<<<(nimg * 50 + THREADS - 1) / THREADS, THREADS, 0, stream>>>(
            ws + p1off, ws, b2, ws + p2off, nimg);
        k_tail<<<(nimg + T_IMG - 1) / T_IMG, 128, 0, stream>>>(
            ws + p2off, ws, b3, fc1w, fc1b, fc2w, fc2b, out, nimg);
    } else {
        lenet_fused<<<(nimg + 1) / 2, THREADS, 0, stream>>>(
            x, w1, b1, w2, b2, w3, b3,
            fc1w, fc1b, fc2w, fc2b, sg1, sr1, sg2, sr2, sg3, sr3, trig, out, nimg);
    }
}

// Round 17
// 228.531 us; speedup vs baseline: 1.0043x; 1.0043x over previous
//
#include <hip/hip_runtime.h>

#define THREADS 256

__device__ __forceinline__ float sigmoidf(float x) {
    return __builtin_amdgcn_rcpf(1.0f + __expf(-x));
}

// ---------------------------------------------------------------------------
// ws layout (floats):
//   [0,168)        e1p : conv1 eff weights, padded [6][28]
//   [168,2856)     e2p : conv2 eff weights, padded [16][6][28]
//   [2856,50856)   e3c : conv3 eff weights, 2-CHANNEL-PER-THREAD layout:
//                        f4[(k*120 + t)*2 + j] = w_eff[2*(t>>1)+j][(t&1)*200+4k..]
//                        t in [0,120), k in [0,50), j in {0,1}. 48000 floats.
//   [54056, +n*1176)  p1 : conv1 pooled out [img][6][196]
//   [.., +n*400)      p2 : conv2 pooled out [img][400]
// ---------------------------------------------------------------------------
#define E2OFF 168
#define E3OFF 2856
#define P1OFF 54056

__global__ void weff_prep(const float* __restrict__ w1, const float* __restrict__ sg1, const int* __restrict__ sr1,
                          const float* __restrict__ w2, const float* __restrict__ sg2, const int* __restrict__ sr2,
                          const float* __restrict__ w3, const float* __restrict__ sg3, const int* __restrict__ sr3,
                          const int* __restrict__ trig, float* __restrict__ ws) {
    int i = blockIdx.x * blockDim.x + threadIdx.x;
    const int t = trig[0];
    if (i < 168) {
        int c = i / 28, k = i % 28;
        float v = 0.f;
        if (k < 25) { int f = c * 25 + k; v = t ? sg1[f] * w1[c * 25 + sr1[f]] : w1[f]; }
        ws[i] = v;
    } else if (i < E3OFF) {
        int j = i - E2OFF;
        int oc = j / 168, r = j % 168, ic = r / 28, k = r % 28;
        float v = 0.f;
        if (k < 25) { int f = oc * 150 + ic * 25 + k; v = t ? sg2[f] * w2[oc * 150 + sr2[f]] : w2[f]; }
        ws[i] = v;
    } else if (i < P1OFF) {
        // 2-channel-per-thread conv3 weights (see layout comment)
        int idx = i - E3OFF;              // 0..51199 (only [0,48000) used)
        if (idx < 48000) {
            int q  = idx & 3;
            int j  = (idx >> 2) & 1;
            int tt = (idx >> 3) % 120;
            int k  = idx / 960;
            int c  = 2 * (tt >> 1) + j;
            int h  = tt & 1;
            int e  = c * 400 + h * 200 + 4 * k + q;
            ws[i] = t ? sg3[e] * w3[c * 400 + sr3[e]] : w3[e];
        } else {
            ws[i] = 0.f;
        }
    }
}

// ---- conv1 (1->6, 5x5) + sigmoid + avgpool2 ----
// thread = (img, pooled row r, pooled col-pair t). Patch 6x8: 2 aligned
// float4 per row. Stores float2 dense. (256,4) is FINAL: R14's (256,6)
// forced VGPR 64->40 -> 379 MB spill. Do not touch the bound.
__global__ __launch_bounds__(THREADS, 4)
void k_conv1(const float* __restrict__ x, const float* __restrict__ ws,
             const float* __restrict__ b1, float* __restrict__ p1, int nimg) {
    __shared__ __align__(16) float lw[176];
    const int tid = threadIdx.x;
    if (tid < 168) lw[tid] = ws[tid];
    if (tid >= 168 && tid < 174) lw[tid] = b1[tid - 168];
    __syncthreads();

    int g = blockIdx.x * THREADS + tid;
    if (g >= nimg * 98) return;
    const int img = g / 98, rem = g % 98;
    const int r = rem / 7, t = rem % 7;

    const float* xb = x + (size_t)img * 1024 + (2 * r) * 32 + 4 * t;
    float pt[6][8];
    #pragma unroll
    for (int rr = 0; rr < 6; ++rr) {
        const float4 v0 = *reinterpret_cast<const float4*>(xb + rr * 32);
        const float4 v1 = *reinterpret_cast<const float4*>(xb + rr * 32 + 4);
        pt[rr][0] = v0.x; pt[rr][1] = v0.y; pt[rr][2] = v0.z; pt[rr][3] = v0.w;
        pt[rr][4] = v1.x; pt[rr][5] = v1.y; pt[rr][6] = v1.z; pt[rr][7] = v1.w;
    }

    #pragma unroll
    for (int c = 0; c < 6; ++c) {
        float z[2][4];
        #pragma unroll
        for (int p = 0; p < 2; ++p)
            #pragma unroll
            for (int w = 0; w < 4; ++w) z[p][w] = 0.f;

        #pragma unroll
        for (int k4 = 0; k4 < 6; ++k4) {
            const float4 w4 = *reinterpret_cast<const float4*>(&lw[c * 28 + 4 * k4]);
            #pragma unroll
            for (int j = 0; j < 4; ++j) {
                const int k = 4 * k4 + j;
                const int ky = k / 5, kx = k % 5;
                const float wv = (j == 0) ? w4.x : (j == 1) ? w4.y : (j == 2) ? w4.z : w4.w;
                #pragma unroll
                for (int p = 0; p < 2; ++p)
                    #pragma unroll
                    for (int dy = 0; dy < 2; ++dy)
                        #pragma unroll
                        for (int dx = 0; dx < 2; ++dx)
                            z[p][2 * dy + dx] += pt[dy + ky][2 * p + dx + kx] * wv;
            }
        }
        { // k = 24 (ky=4, kx=4)
            const float wv = lw[c * 28 + 24];
            #pragma unroll
            for (int p = 0; p < 2; ++p)
                #pragma unroll
                for (int dy = 0; dy < 2; ++dy)
                    #pragma unroll
                    for (int dx = 0; dx < 2; ++dx)
                        z[p][2 * dy + dx] += pt[dy + 4][2 * p + dx + 4] * wv;
        }

        const float bb = lw[168 + c];
        const float s0 = sigmoidf(z[0][0] + bb) + sigmoidf(z[0][1] + bb) +
                         sigmoidf(z[0][2] + bb) + sigmoidf(z[0][3] + bb);
        const float s1 = sigmoidf(z[1][0] + bb) + sigmoidf(z[1][1] + bb) +
                         sigmoidf(z[1][2] + bb) + sigmoidf(z[1][3] + bb);
        *reinterpret_cast<float2*>(&p1[((size_t)img * 6 + c) * 196 + r * 14 + 2 * t]) =
            make_float2(0.25f * s0, 0.25f * s1);
    }
}

// ---- conv2 (6->16, 5x5) + sigmoid + avgpool2 -- LDS patches + s_load weights
// Block = 5 images staged in LDS (23.5 KB; 4 blocks/CU = 94 KB < 160).
// R16 showed occupancy was NOT the limiter (46% pinned, dur 113): the idle
// was VMEM latency on the 90 inner-loop float2 patch loads. Now patches come
// from LDS (90 ds_read_b64/thread ~ 11us/CU of LDS pipe -- cheap; R3's
// LDS-bound failure was WEIGHTS in LDS, 672 b128/wave) and weights stay on
// the scalar pipe (loop-uniform s_load, R11 lesson). Zero inner-loop VMEM.
#define C2I 5
__global__ __launch_bounds__(THREADS, 4)
void k_conv2(const float* __restrict__ p1, const float* __restrict__ ws,
             const float* __restrict__ b2, float* __restrict__ p2, int nimg) {
    __shared__ __align__(16) float sp1[C2I * 1176];
    const int tid = threadIdx.x;
    const int img0 = blockIdx.x * C2I;

    // stage 5 images of p1: 5*294 float4, coalesced, read once
    for (int i = tid; i < C2I * 294; i += THREADS) {
        const int im = i / 294, off = i % 294;
        const int gi = min(img0 + im, nimg - 1);
        reinterpret_cast<float4*>(&sp1[im * 1176])[off] =
            reinterpret_cast<const float4*>(p1 + (size_t)gi * 1176)[off];
    }
    __syncthreads();

    if (tid >= C2I * 50) return;
    const int iml = tid / 50, rem = tid % 50;
    const int img = img0 + iml;
    if (img >= nimg) return;
    const int pix = rem >> 1, di = rem & 1;
    const int pi = pix / 5, pj = pix % 5;
    const float* pimg = &sp1[iml * 1176 + (2 * pi + di) * 14 + 2 * pj];
    const float* wq = ws + E2OFF;

    float acc[16][2];
    #pragma unroll
    for (int oc = 0; oc < 16; ++oc) { acc[oc][0] = 0.f; acc[oc][1] = 0.f; }

    #pragma unroll 2
    for (int ic = 0; ic < 6; ++ic) {
        float pt[5][6];
        const float* pb = pimg + ic * 196;
        #pragma unroll
        for (int r = 0; r < 5; ++r) {
            #pragma unroll
            for (int cc = 0; cc < 3; ++cc) {
                float2 v = *reinterpret_cast<const float2*>(pb + r * 14 + 2 * cc);
                pt[r][2 * cc] = v.x; pt[r][2 * cc + 1] = v.y;
            }
        }
        #pragma unroll
        for (int oc = 0; oc < 16; ++oc) {
            const float* wr = wq + oc * 168 + ic * 28;   // uniform (loop vars)
            #pragma unroll
            for (int k4 = 0; k4 < 6; ++k4) {
                const float4 w4 = *reinterpret_cast<const float4*>(wr + 4 * k4);
                #pragma unroll
                for (int j = 0; j < 4; ++j) {
                    const int k = 4 * k4 + j;
                    const int ky = k / 5, kx = k % 5;
                    const float wv = (j == 0) ? w4.x : (j == 1) ? w4.y : (j == 2) ? w4.z : w4.w;
                    acc[oc][0] += pt[ky][kx] * wv;
                    acc[oc][1] += pt[ky][kx + 1] * wv;
                }
            }
            const float wv = wr[24];
            acc[oc][0] += pt[4][4] * wv;
            acc[oc][1] += pt[4][5] * wv;
        }
    }

    #pragma unroll
    for (int oc = 0; oc < 16; ++oc) {
        const float bb = b2[oc];
        float s = sigmoidf(acc[oc][0] + bb) + sigmoidf(acc[oc][1] + bb);
        s += __shfl_xor(s, 1, 64);     // combine di=0 / di=1 (adjacent lanes)
        if (di == 0)
            p2[(size_t)img * 400 + oc * 25 + pix] = 0.25f * s;
    }
}

// ---- conv3 (16->120) + sigmoid, fc1 + sigmoid, fc2 -- 2 ch/thread ----
// Thread t=(cpair,h) owns channels 2*cpair, 2*cpair+1: each u ds_read feeds
// 8 FMAs -> 800 wave ds_reads/block (~32us LDS-pipe). Weights via e3c:
// 32 B/lane contiguous, 2 KB/wave dense. h-partners adjacent ->
// __shfl_xor(s,1). acc[2][8] scalars ~75 VGPR < (128,4)'s cap.
#define T_IMG 8
__global__ __launch_bounds__(128, 4)
void k_tail(const float* __restrict__ p2, const float* __restrict__ ws,
            const float* __restrict__ b3,
            const float* __restrict__ fc1w, const float* __restrict__ fc1b,
            const float* __restrict__ fc2w, const float* __restrict__ fc2b,
            float* __restrict__ out, int nimg) {
    __shared__ __align__(16) float sp2[T_IMG][400];
    __shared__ __align__(16) float v3[T_IMG][120];
    __shared__ __align__(16) float v4[T_IMG][84];
    const int tid = threadIdx.x;
    const int img0 = blockIdx.x * T_IMG;

    for (int i = tid; i < T_IMG * 100; i += 128) {
        const int im = i / 100, off = i % 100;
        const int gi = min(img0 + im, nimg - 1);
        reinterpret_cast<float4*>(&sp2[im][0])[off] =
            reinterpret_cast<const float4*>(p2 + (size_t)gi * 400)[off];
    }
    __syncthreads();

    if (tid < 120) {
        const int h = tid & 1;
        const int cpair = tid >> 1;
        float acc[2][T_IMG];
        #pragma unroll
        for (int j = 0; j < 2; ++j)
            #pragma unroll
            for (int im = 0; im < T_IMG; ++im) acc[j][im] = 0.f;

        const float4* wp = reinterpret_cast<const float4*>(ws + E3OFF);
        #pragma unroll 2
        for (int k = 0; k < 50; ++k) {
            const float4 w0 = wp[(k * 120 + tid) * 2];
            const float4 w1 = wp[(k * 120 + tid) * 2 + 1];
            #pragma unroll
            for (int im = 0; im < T_IMG; ++im) {
                const float4 u = *reinterpret_cast<const float4*>(&sp2[im][h * 200 + 4 * k]);
                acc[0][im] += w0.x * u.x + w0.y * u.y + w0.z * u.z + w0.w * u.w;
                acc[1][im] += w1.x * u.x + w1.y * u.y + w1.z * u.z + w1.w * u.w;
            }
        }
        #pragma unroll
        for (int j = 0; j < 2; ++j) {
            const int c = 2 * cpair + j;
            const float bb = b3[c];
            #pragma unroll
            for (int im = 0; im < T_IMG; ++im) {
                float s = acc[j][im];
                s += __shfl_xor(s, 1, 64);   // combine h=0/h=1 (adjacent lanes)
                if (h == 0) v3[im][c] = sigmoidf(s + bb);
            }
        }
    }
    __syncthreads();

    for (int it = tid; it < T_IMG * 84; it += 128) {
        const int im = it / 84, j = it % 84;
        const float4* wp = reinterpret_cast<const float4*>(fc1w + j * 120);
        const float4* vp = reinterpret_cast<const float4*>(&v3[im][0]);
        float4 a = make_float4(0.f, 0.f, 0.f, 0.f);
        #pragma unroll 6
        for (int k = 0; k < 30; ++k) {
            const float4 w4 = wp[k];
            const float4 u = vp[k];
            a.x += u.x * w4.x; a.y += u.y * w4.y;
            a.z += u.z * w4.z; a.w += u.w * w4.w;
        }
        v4[im][j] = sigmoidf((a.x + a.y) + (a.z + a.w) + fc1b[j]);
    }
    __syncthreads();

    if (tid < T_IMG * 10) {
        const int im = tid / 10, j = tid % 10;
        if (img0 + im < nimg) {
            const float4* wp = reinterpret_cast<const float4*>(fc2w + j * 84);
            const float4* vp = reinterpret_cast<const float4*>(&v4[im][0]);
            float4 a = make_float4(0.f, 0.f, 0.f, 0.f);
            #pragma unroll
            for (int k = 0; k < 21; ++k) {
                const float4 w4 = wp[k];
                const float4 u = vp[k];
                a.x += u.x * w4.x; a.y += u.y * w4.y;
                a.z += u.z * w4.z; a.w += u.w * w4.w;
            }
            out[(size_t)(img0 + im) * 10 + j] = (a.x + a.y) + (a.z + a.w) + fc2b[j];
        }
    }
}

// ---------------- fallback: single fused kernel, inline gather ----------------
__device__ __forceinline__ float wget_ig(const float* __restrict__ wp,
                                         const float* __restrict__ sg,
                                         const int* __restrict__ sr,
                                         int row, int m, int idx, bool tg) {
    int f = row * m + idx;
    return tg ? sg[f] * wp[row * m + sr[f]] : wp[f];
}

__global__ __launch_bounds__(THREADS, 4)
void lenet_fused(const float* __restrict__ x,
                 const float* __restrict__ w1e, const float* __restrict__ b1,
                 const float* __restrict__ w2e, const float* __restrict__ b2,
                 const float* __restrict__ w3e, const float* __restrict__ b3,
                 const float* __restrict__ fc1w, const float* __restrict__ fc1b,
                 const float* __restrict__ fc2w, const float* __restrict__ fc2b,
                 const float* __restrict__ sg1, const int* __restrict__ sr1,
                 const float* __restrict__ sg2, const int* __restrict__ sr2,
                 const float* __restrict__ sg3, const int* __restrict__ sr3,
                 const int* __restrict__ trig,
                 float* __restrict__ out, int nimg) {
    const int tid = threadIdx.x;
    const int img0 = blockIdx.x * 2;
    __shared__ __align__(16) float xs[2][1024];
    __shared__ __align__(16) float p1[2][6][196];
    __shared__ __align__(16) float p2[2][400];
    __shared__ __align__(16) float v3[2][120];
    __shared__ __align__(16) float v4[2][84];
    const bool tg = trig[0] != 0;

    #pragma unroll
    for (int im = 0; im < 2; ++im) {
        int gi = min(img0 + im, nimg - 1);
        reinterpret_cast<float4*>(&xs[im][0])[tid] =
            reinterpret_cast<const float4*>(x + (size_t)gi * 1024)[tid];
    }
    __syncthreads();

    for (int it = tid; it < 2 * 196; it += THREADS) {
        const int img = it / 196, pix = it % 196;
        const int pi = pix / 14, pj = pix % 14;
        const float* xb = &xs[img][(2 * pi) * 32 + 2 * pj];
        float pt[6][6];
        #pragma unroll
        for (int r = 0; r < 6; ++r)
            #pragma unroll
            for (int cc = 0; cc < 3; ++cc) {
                float2 v = *reinterpret_cast<const float2*>(&xb[r * 32 + cc * 2]);
                pt[r][cc * 2] = v.x; pt[r][cc * 2 + 1] = v.y;
            }
        #pragma unroll
        for (int c = 0; c < 6; ++c) {
            float z0 = 0.f, z1 = 0.f, z2 = 0.f, z3 = 0.f;
            #pragma unroll
            for (int ky = 0; ky < 5; ++ky)
                #pragma unroll
                for (int kx = 0; kx < 5; ++kx) {
                    const float wv = wget_ig(w1e, sg1, sr1, c, 25, ky * 5 + kx, tg);
                    z0 += pt[ky][kx] * wv;     z1 += pt[ky][kx + 1] * wv;
                    z2 += pt[ky + 1][kx] * wv; z3 += pt[ky + 1][kx + 1] * wv;
                }
            const float bb = b1[c];
            p1[img][c][pix] = 0.25f * (sigmoidf(z0 + bb) + sigmoidf(z1 + bb) +
                                       sigmoidf(z2 + bb) + sigmoidf(z3 + bb));
        }
    }
    __syncthreads();

    if (tid < 200) {
        const int img = tid / 100, rem = tid % 100;
        const int pix = rem >> 2, win = rem & 3;
        const int di = win >> 1, dj = win & 1;
        const int pi = pix / 5, pj = pix % 5;
        const int r0 = 2 * pi + di, c0 = 2 * pj + dj;
        float acc[16];
        #pragma unroll
        for (int c = 0; c < 16; ++c) acc[c] = 0.f;
        for (int ic = 0; ic < 6; ++ic) {
            float pt[5][5];
            #pragma unroll
            for (int ky = 0; ky < 5; ++ky)
                #pragma unroll
                for (int kx = 0; kx < 5; ++kx)
                    pt[ky][kx] = p1[img][ic][(r0 + ky) * 14 + (c0 + kx)];
            #pragma unroll
            for (int c = 0; c < 16; ++c) {
                float z = acc[c];
                #pragma unroll
                for (int ky = 0; ky < 5; ++ky)
                    #pragma unroll
                    for (int kx = 0; kx < 5; ++kx)
                        z += pt[ky][kx] * wget_ig(w2e, sg2, sr2, c, 150, ic * 25 + ky * 5 + kx, tg);
                acc[c] = z;
            }
        }
        #pragma unroll
        for (int c = 0; c < 16; ++c) {
            float z = sigmoidf(acc[c] + b2[c]);
            z += __shfl_xor(z, 1, 64);
            z += __shfl_xor(z, 2, 64);
            if (win == 0) p2[img][c * 25 + pix] = 0.25f * z;
        }
    }
    __syncthreads();

    if (tid < 240) {
        const int c = tid >> 1, h = tid & 1;
        float s0 = 0.f, s1 = 0.f;
        for (int k = 0; k < 200; ++k) {
            float wv = wget_ig(w3e, sg3, sr3, c, 400, h * 200 + k, tg);
            s0 += p2[0][h * 200 + k] * wv;
            s1 += p2[1][h * 200 + k] * wv;
        }
        s0 += __shfl_xor(s0, 1, 64);
        s1 += __shfl_xor(s1, 1, 64);
        if (h == 0) {
            const float bb = b3[c];
            v3[0][c] = sigmoidf(s0 + bb);
            v3[1][c] = sigmoidf(s1 + bb);
        }
    }
    __syncthreads();

    if (tid < 168) {
        const int img = tid / 84, j = tid % 84;
        float a = 0.f;
        for (int k = 0; k < 120; ++k) a += v3[img][k] * fc1w[j * 120 + k];
        v4[img][j] = sigmoidf(a + fc1b[j]);
    }
    __syncthreads();

    if (tid < 20) {
        const int img = tid / 10, j = tid % 10;
        if (img0 + img < nimg) {
            float a = 0.f;
            for (int k = 0; k < 84; ++k) a += v4[img][k] * fc2w[j * 84 + k];
            out[(size_t)(img0 + img) * 10 + j] = a + fc2b[j];
        }
    }
}

extern "C" void kernel_launch(void* const* d_in, const int* in_sizes, int n_in,
                              void* d_out, int out_size, void* d_ws, size_t ws_size,
                              hipStream_t stream) {
    const float* x    = (const float*)d_in[0];
    const float* w1   = (const float*)d_in[1];
    const float* b1   = (const float*)d_in[2];
    const float* sg1  = (const float*)d_in[3];
    const float* w2   = (const float*)d_in[4];
    const float* b2   = (const float*)d_in[5];
    const float* sg2  = (const float*)d_in[6];
    const float* w3   = (const float*)d_in[7];
    const float* b3   = (const float*)d_in[8];
    const float* sg3  = (const float*)d_in[9];
    const float* fc1w = (const float*)d_in[10];
    const float* fc1b = (const float*)d_in[11];
    const float* fc2w = (const float*)d_in[12];
    const float* fc2b = (const float*)d_in[13];
    const int*   sr1  = (const int*)d_in[14];
    const int*   sr2  = (const int*)d_in[15];
    const int*   sr3  = (const int*)d_in[16];
    const int*   trig = (const int*)d_in[17];

    const int nimg = in_sizes[0] / 1024;
    float* out = (float*)d_out;

    const size_t p1off = P1OFF;
    const size_t p2off = p1off + (size_t)nimg * 1176;
    const size_t need_bytes = (p2off + (size_t)nimg * 400) * sizeof(float);

    if (ws_size >= need_bytes) {
        float* ws = (float*)d_ws;
        weff_prep<<<(P1OFF + 255) / 256, 256, 0, stream>>>(
            w1, sg1, sr1, w2, sg2, sr2, w3, sg3, sr3, trig, ws);
        k_conv1<<<(nimg * 98 + THREADS - 1) / THREADS, THREADS, 0, stream>>>(
            x, ws, b1, ws + p1off, nimg);
        k_conv2<<<(nimg + C2I - 1) / C2I, THREADS, 0, stream>>>(
            ws + p1off, ws, b2, ws + p2off, nimg);
        k_tail<<<(nimg + T_IMG - 1) / T_IMG, 128, 0, stream>>>(
            ws + p2off, ws, b3, fc1w, fc1b, fc2w, fc2b, out, nimg);
    } else {
        lenet_fused<<<(nimg + 1) / 2, THREADS, 0, stream>>>(
            x, w1, b1, w2, b2, w3, b3,
            fc1w, fc1b, fc2w, fc2b, sg1, sr1, sg2, sr2, sg3, sr3, trig, out, nimg);
    }
}

// Round 19
// 219.593 us; speedup vs baseline: 1.0451x; 1.0407x over previous
//
#include <hip/hip_runtime.h>

#define THREADS 256

typedef _Float16 half2v __attribute__((ext_vector_type(2)));
typedef __fp16   half2p __attribute__((ext_vector_type(2)));

__device__ __forceinline__ float sigmoidf(float x) {
    return __builtin_amdgcn_rcpf(1.0f + __expf(-x));
}

__device__ __forceinline__ half2v f2h2(float f) {
    union { float f; half2v h; } u; u.f = f; return u.h;
}

__device__ __forceinline__ half2v pk2h2(half2p p) {
    union { half2p p; half2v h; } u; u.p = p; return u.h;
}

// ---------------------------------------------------------------------------
// ws layout (floats):
//   [0,168)        e1p : conv1 eff weights, padded [6][28]
//   [168,1704)     e2k : conv2 eff weights, F16-PACKED layout [16 oc][6 ic][16]:
//                        slot 2*kx+p (p in {0,1}, kx in 0..4) = uint half2
//                        (w[ky=2p][kx] lo, w[ky=2p+1][kx] hi); slot 10+kx =
//                        f32 w[ky=4][kx]; slot 15 pad. 1536 floats.
//   [1704,2856)    unused (zeroed)
//   [2856,50856)   e3c : conv3 eff weights, 2-CHANNEL-PER-THREAD layout:
//                        f4[(k*120 + t)*2 + j] = w_eff[2*(t>>1)+j][(t&1)*200+4k..]
//   [54056, +n*1176)  p1 : conv1 pooled out [img][6][196]
//   [.., +n*400)      p2 : conv2 pooled out [img][400]
// ---------------------------------------------------------------------------
#define E2OFF 168
#define E3OFF 2856
#define P1OFF 54056

__global__ void weff_prep(const float* __restrict__ w1, const float* __restrict__ sg1, const int* __restrict__ sr1,
                          const float* __restrict__ w2, const float* __restrict__ sg2, const int* __restrict__ sr2,
                          const float* __restrict__ w3, const float* __restrict__ sg3, const int* __restrict__ sr3,
                          const int* __restrict__ trig, float* __restrict__ ws) {
    int i = blockIdx.x * blockDim.x + threadIdx.x;
    const int t = trig[0];
    if (i < 168) {
        int c = i / 28, k = i % 28;
        float v = 0.f;
        if (k < 25) { int f = c * 25 + k; v = t ? sg1[f] * w1[c * 25 + sr1[f]] : w1[f]; }
        ws[i] = v;
    } else if (i < 1704) {
        // f16-packed conv2 weights
        int j = i - E2OFF;
        int oc = j / 96, r = j % 96, ic = r / 16, slot = r % 16;
        const int base = oc * 150 + ic * 25;
        float outv = 0.f;
        if (slot < 10) {
            int kx = slot >> 1, p = slot & 1;
            int k0 = base + (2 * p) * 5 + kx;
            int k1 = base + (2 * p + 1) * 5 + kx;
            float v0 = t ? sg2[k0] * w2[oc * 150 + sr2[k0]] : w2[k0];
            float v1 = t ? sg2[k1] * w2[oc * 150 + sr2[k1]] : w2[k1];
            union { _Float16 h[2]; float f; } pun;
            pun.h[0] = (_Float16)v0;
            pun.h[1] = (_Float16)v1;
            outv = pun.f;
        } else if (slot < 15) {
            int kx = slot - 10;
            int k4 = base + 20 + kx;
            outv = t ? sg2[k4] * w2[oc * 150 + sr2[k4]] : w2[k4];
        }
        ws[i] = outv;
    } else if (i < E3OFF) {
        ws[i] = 0.f;
    } else if (i < P1OFF) {
        // 2-channel-per-thread conv3 weights
        int idx = i - E3OFF;
        if (idx < 48000) {
            int q  = idx & 3;
            int j  = (idx >> 2) & 1;
            int tt = (idx >> 3) % 120;
            int k  = idx / 960;
            int c  = 2 * (tt >> 1) + j;
            int h  = tt & 1;
            int e  = c * 400 + h * 200 + 4 * k + q;
            ws[i] = t ? sg3[e] * w3[c * 400 + sr3[e]] : w3[e];
        } else {
            ws[i] = 0.f;
        }
    }
}

// ---- conv1 (1->6, 5x5) + sigmoid + avgpool2 ---- (R15 body, FINAL bounds)
__global__ __launch_bounds__(THREADS, 4)
void k_conv1(const float* __restrict__ x, const float* __restrict__ ws,
             const float* __restrict__ b1, float* __restrict__ p1, int nimg) {
    __shared__ __align__(16) float lw[176];
    const int tid = threadIdx.x;
    if (tid < 168) lw[tid] = ws[tid];
    if (tid >= 168 && tid < 174) lw[tid] = b1[tid - 168];
    __syncthreads();

    int g = blockIdx.x * THREADS + tid;
    if (g >= nimg * 98) return;
    const int img = g / 98, rem = g % 98;
    const int r = rem / 7, t = rem % 7;

    const float* xb = x + (size_t)img * 1024 + (2 * r) * 32 + 4 * t;
    float pt[6][8];
    #pragma unroll
    for (int rr = 0; rr < 6; ++rr) {
        const float4 v0 = *reinterpret_cast<const float4*>(xb + rr * 32);
        const float4 v1 = *reinterpret_cast<const float4*>(xb + rr * 32 + 4);
        pt[rr][0] = v0.x; pt[rr][1] = v0.y; pt[rr][2] = v0.z; pt[rr][3] = v0.w;
        pt[rr][4] = v1.x; pt[rr][5] = v1.y; pt[rr][6] = v1.z; pt[rr][7] = v1.w;
    }

    #pragma unroll
    for (int c = 0; c < 6; ++c) {
        float z[2][4];
        #pragma unroll
        for (int p = 0; p < 2; ++p)
            #pragma unroll
            for (int w = 0; w < 4; ++w) z[p][w] = 0.f;

        #pragma unroll
        for (int k4 = 0; k4 < 6; ++k4) {
            const float4 w4 = *reinterpret_cast<const float4*>(&lw[c * 28 + 4 * k4]);
            #pragma unroll
            for (int j = 0; j < 4; ++j) {
                const int k = 4 * k4 + j;
                const int ky = k / 5, kx = k % 5;
                const float wv = (j == 0) ? w4.x : (j == 1) ? w4.y : (j == 2) ? w4.z : w4.w;
                #pragma unroll
                for (int p = 0; p < 2; ++p)
                    #pragma unroll
                    for (int dy = 0; dy < 2; ++dy)
                        #pragma unroll
                        for (int dx = 0; dx < 2; ++dx)
                            z[p][2 * dy + dx] += pt[dy + ky][2 * p + dx + kx] * wv;
            }
        }
        {
            const float wv = lw[c * 28 + 24];
            #pragma unroll
            for (int p = 0; p < 2; ++p)
                #pragma unroll
                for (int dy = 0; dy < 2; ++dy)
                    #pragma unroll
                    for (int dx = 0; dx < 2; ++dx)
                        z[p][2 * dy + dx] += pt[dy + 4][2 * p + dx + 4] * wv;
        }

        const float bb = lw[168 + c];
        const float s0 = sigmoidf(z[0][0] + bb) + sigmoidf(z[0][1] + bb) +
                         sigmoidf(z[0][2] + bb) + sigmoidf(z[0][3] + bb);
        const float s1 = sigmoidf(z[1][0] + bb) + sigmoidf(z[1][1] + bb) +
                         sigmoidf(z[1][2] + bb) + sigmoidf(z[1][3] + bb);
        *reinterpret_cast<float2*>(&p1[((size_t)img * 6 + c) * 196 + r * 14 + 2 * t]) =
            make_float2(0.25f * s0, 0.25f * s1);
    }
}

// ---- conv2 (6->16, 5x5) + sigmoid + avgpool2 -- f16 dot2 ----
// R10/R13/R16/R17 all pinned at ~113us, VALUBusy ~60-64% across occupancy /
// VMEM / LDS variants -> ISSUE-bound (71us issued vs 50us useful FMA). Fix:
// fewer instructions per FLOP via v_dot2_f32_f16. Per (ic,oc): one
// s_load_dwordx16 (weights f16-packed along ky, loop-uniform -> scalar pipe)
// + 5 kx x 2 dx x (2 fdot2 + 1 fma) = 30 VALU vs 50. Patches fp32 from
// global (R13 base), packed 12 cvt_pkrtz per ic. fp32 accumulate; absmax
// margin 6x covers the f16 rounding (est +2e-3).
__global__ __launch_bounds__(THREADS, 3)
void k_conv2(const float* __restrict__ p1, const float* __restrict__ ws,
             const float* __restrict__ b2, float* __restrict__ p2, int nimg) {
    int g = blockIdx.x * THREADS + threadIdx.x;
    if (g >= nimg * 50) return;
    const int img = g / 50, rem = g % 50;
    const int pix = rem >> 1, di = rem & 1;
    const int pi = pix / 5, pj = pix % 5;
    const float* pimg = p1 + (size_t)img * 1176 + (2 * pi + di) * 14 + 2 * pj;
    const float* wq = ws + E2OFF;

    float acc[16][2];
    #pragma unroll
    for (int oc = 0; oc < 16; ++oc) { acc[oc][0] = 0.f; acc[oc][1] = 0.f; }

    for (int ic = 0; ic < 6; ++ic) {
        float pt[5][6];
        const float* pb = pimg + ic * 196;
        #pragma unroll
        for (int r = 0; r < 5; ++r) {
            #pragma unroll
            for (int cc = 0; cc < 3; ++cc) {
                float2 v = *reinterpret_cast<const float2*>(pb + r * 14 + 2 * cc);
                pt[r][2 * cc] = v.x; pt[r][2 * cc + 1] = v.y;
            }
        }
        // pack vertical ky-pairs to half2 (rtz; error covered by margin)
        half2v pk01[6], pk23[6];
        #pragma unroll
        for (int cc = 0; cc < 6; ++cc) {
            pk01[cc] = pk2h2(__builtin_amdgcn_cvt_pkrtz(pt[0][cc], pt[1][cc]));
            pk23[cc] = pk2h2(__builtin_amdgcn_cvt_pkrtz(pt[2][cc], pt[3][cc]));
        }
        #pragma unroll
        for (int oc = 0; oc < 16; ++oc) {
            const float* wrow = wq + (oc * 6 + ic) * 16;   // uniform -> s_load_dwordx16
            #pragma unroll
            for (int kx = 0; kx < 5; ++kx) {
                const half2v wa = f2h2(wrow[2 * kx]);       // ky 0,1
                const half2v wb = f2h2(wrow[2 * kx + 1]);   // ky 2,3
                const float  wf = wrow[10 + kx];            // ky 4
                acc[oc][0] = __builtin_amdgcn_fdot2(pk01[kx], wa, acc[oc][0], false);
                acc[oc][0] = __builtin_amdgcn_fdot2(pk23[kx], wb, acc[oc][0], false);
                acc[oc][0] += pt[4][kx] * wf;
                acc[oc][1] = __builtin_amdgcn_fdot2(pk01[kx + 1], wa, acc[oc][1], false);
                acc[oc][1] = __builtin_amdgcn_fdot2(pk23[kx + 1], wb, acc[oc][1], false);
                acc[oc][1] += pt[4][kx + 1] * wf;
            }
        }
    }

    #pragma unroll
    for (int oc = 0; oc < 16; ++oc) {
        const float bb = b2[oc];
        float s = sigmoidf(acc[oc][0] + bb) + sigmoidf(acc[oc][1] + bb);
        s += __shfl_xor(s, 1, 64);     // combine di=0 / di=1 (adjacent lanes)
        if (di == 0)
            p2[(size_t)img * 400 + oc * 25 + pix] = 0.25f * s;
    }
}

// ---- conv3 (16->120) + sigmoid, fc1 + sigmoid, fc2 -- 2 ch/thread (R15) ----
#define T_IMG 8
__global__ __launch_bounds__(128, 4)
void k_tail(const float* __restrict__ p2, const float* __restrict__ ws,
            const float* __restrict__ b3,
            const float* __restrict__ fc1w, const float* __restrict__ fc1b,
            const float* __restrict__ fc2w, const float* __restrict__ fc2b,
            float* __restrict__ out, int nimg) {
    __shared__ __align__(16) float sp2[T_IMG][400];
    __shared__ __align__(16) float v3[T_IMG][120];
    __shared__ __align__(16) float v4[T_IMG][84];
    const int tid = threadIdx.x;
    const int img0 = blockIdx.x * T_IMG;

    for (int i = tid; i < T_IMG * 100; i += 128) {
        const int im = i / 100, off = i % 100;
        const int gi = min(img0 + im, nimg - 1);
        reinterpret_cast<float4*>(&sp2[im][0])[off] =
            reinterpret_cast<const float4*>(p2 + (size_t)gi * 400)[off];
    }
    __syncthreads();

    if (tid < 120) {
        const int h = tid & 1;
        const int cpair = tid >> 1;
        float acc[2][T_IMG];
        #pragma unroll
        for (int j = 0; j < 2; ++j)
            #pragma unroll
            for (int im = 0; im < T_IMG; ++im) acc[j][im] = 0.f;

        const float4* wp = reinterpret_cast<const float4*>(ws + E3OFF);
        #pragma unroll 2
        for (int k = 0; k < 50; ++k) {
            const float4 w0 = wp[(k * 120 + tid) * 2];
            const float4 w1 = wp[(k * 120 + tid) * 2 + 1];
            #pragma unroll
            for (int im = 0; im < T_IMG; ++im) {
                const float4 u = *reinterpret_cast<const float4*>(&sp2[im][h * 200 + 4 * k]);
                acc[0][im] += w0.x * u.x + w0.y * u.y + w0.z * u.z + w0.w * u.w;
                acc[1][im] += w1.x * u.x + w1.y * u.y + w1.z * u.z + w1.w * u.w;
            }
        }
        #pragma unroll
        for (int j = 0; j < 2; ++j) {
            const int c = 2 * cpair + j;
            const float bb = b3[c];
            #pragma unroll
            for (int im = 0; im < T_IMG; ++im) {
                float s = acc[j][im];
                s += __shfl_xor(s, 1, 64);
                if (h == 0) v3[im][c] = sigmoidf(s + bb);
            }
        }
    }
    __syncthreads();

    for (int it = tid; it < T_IMG * 84; it += 128) {
        const int im = it / 84, j = it % 84;
        const float4* wp = reinterpret_cast<const float4*>(fc1w + j * 120);
        const float4* vp = reinterpret_cast<const float4*>(&v3[im][0]);
        float4 a = make_float4(0.f, 0.f, 0.f, 0.f);
        #pragma unroll 6
        for (int k = 0; k < 30; ++k) {
            const float4 w4 = wp[k];
            const float4 u = vp[k];
            a.x += u.x * w4.x; a.y += u.y * w4.y;
            a.z += u.z * w4.z; a.w += u.w * w4.w;
        }
        v4[im][j] = sigmoidf((a.x + a.y) + (a.z + a.w) + fc1b[j]);
    }
    __syncthreads();

    if (tid < T_IMG * 10) {
        const int im = tid / 10, j = tid % 10;
        if (img0 + im < nimg) {
            const float4* wp = reinterpret_cast<const float4*>(fc2w + j * 84);
            const float4* vp = reinterpret_cast<const float4*>(&v4[im][0]);
            float4 a = make_float4(0.f, 0.f, 0.f, 0.f);
            #pragma unroll
            for (int k = 0; k < 21; ++k) {
                const float4 w4 = wp[k];
                const float4 u = vp[k];
                a.x += u.x * w4.x; a.y += u.y * w4.y;
                a.z += u.z * w4.z; a.w += u.w * w4.w;
            }
            out[(size_t)(img0 + im) * 10 + j] = (a.x + a.y) + (a.z + a.w) + fc2b[j];
        }
    }
}

// ---------------- fallback: single fused kernel, inline gather ----------------
__device__ __forceinline__ float wget_ig(const float* __restrict__ wp,
                                         const float* __restrict__ sg,
                                         const int* __restrict__ sr,
                                         int row, int m, int idx, bool tg) {
    int f = row * m + idx;
    return tg ? sg[f] * wp[row * m + sr[f]] : wp[f];
}

__global__ __launch_bounds__(THREADS, 4)
void lenet_fused(const float* __restrict__ x,
                 const float* __restrict__ w1e, const float* __restrict__ b1,
                 const float* __restrict__ w2e, const float* __restrict__ b2,
                 const float* __restrict__ w3e, const float* __restrict__ b3,
                 const float* __restrict__ fc1w, const float* __restrict__ fc1b,
                 const float* __restrict__ fc2w, const float* __restrict__ fc2b,
                 const float* __restrict__ sg1, const int* __restrict__ sr1,
                 const float* __restrict__ sg2, const int* __restrict__ sr2,
                 const float* __restrict__ sg3, const int* __restrict__ sr3,
                 const int* __restrict__ trig,
                 float* __restrict__ out, int nimg) {
    const int tid = threadIdx.x;
    const int img0 = blockIdx.x * 2;
    __shared__ __align__(16) float xs[2][1024];
    __shared__ __align__(16) float p1[2][6][196];
    __shared__ __align__(16) float p2[2][400];
    __shared__ __align__(16) float v3[2][120];
    __shared__ __align__(16) float v4[2][84];
    const bool tg = trig[0] != 0;

    #pragma unroll
    for (int im = 0; im < 2; ++im) {
        int gi = min(img0 + im, nimg - 1);
        reinterpret_cast<float4*>(&xs[im][0])[tid] =
            reinterpret_cast<const float4*>(x + (size_t)gi * 1024)[tid];
    }
    __syncthreads();

    for (int it = tid; it < 2 * 196; it += THREADS) {
        const int img = it / 196, pix = it % 196;
        const int pi = pix / 14, pj = pix % 14;
        const float* xb = &xs[img][(2 * pi) * 32 + 2 * pj];
        float pt[6][6];
        #pragma unroll
        for (int r = 0; r < 6; ++r)
            #pragma unroll
            for (int cc = 0; cc < 3; ++cc) {
                float2 v = *reinterpret_cast<const float2*>(&xb[r * 32 + cc * 2]);
                pt[r][cc * 2] = v.x; pt[r][cc * 2 + 1] = v.y;
            }
        #pragma unroll
        for (int c = 0; c < 6; ++c) {
            float z0 = 0.f, z1 = 0.f, z2 = 0.f, z3 = 0.f;
            #pragma unroll
            for (int ky = 0; ky < 5; ++ky)
                #pragma unroll
                for (int kx = 0; kx < 5; ++kx) {
                    const float wv = wget_ig(w1e, sg1, sr1, c, 25, ky * 5 + kx, tg);
                    z0 += pt[ky][kx] * wv;     z1 += pt[ky][kx + 1] * wv;
                    z2 += pt[ky + 1][kx] * wv; z3 += pt[ky + 1][kx + 1] * wv;
                }
            const float bb = b1[c];
            p1[img][c][pix] = 0.25f * (sigmoidf(z0 + bb) + sigmoidf(z1 + bb) +
                                       sigmoidf(z2 + bb) + sigmoidf(z3 + bb));
        }
    }
    __syncthreads();

    if (tid < 200) {
        const int img = tid / 100, rem = tid % 100;
        const int pix = rem >> 2, win = rem & 3;
        const int di = win >> 1, dj = win & 1;
        const int pi = pix / 5, pj = pix % 5;
        const int r0 = 2 * pi + di, c0 = 2 * pj + dj;
        float acc[16];
        #pragma unroll
        for (int c = 0; c < 16; ++c) acc[c] = 0.f;
        for (int ic = 0; ic < 6; ++ic) {
            float pt[5][5];
            #pragma unroll
            for (int ky = 0; ky < 5; ++ky)
                #pragma unroll
                for (int kx = 0; kx < 5; ++kx)
                    pt[ky][kx] = p1[img][ic][(r0 + ky) * 14 + (c0 + kx)];
            #pragma unroll
            for (int c = 0; c < 16; ++c) {
                float z = acc[c];
                #pragma unroll
                for (int ky = 0; ky < 5; ++ky)
                    #pragma unroll
                    for (int kx = 0; kx < 5; ++kx)
                        z += pt[ky][kx] * wget_ig(w2e, sg2, sr2, c, 150, ic * 25 + ky * 5 + kx, tg);
                acc[c] = z;
            }
        }
        #pragma unroll
        for (int c = 0; c < 16; ++c) {
            float z = sigmoidf(acc[c] + b2[c]);
            z += __shfl_xor(z, 1, 64);
            z += __shfl_xor(z, 2, 64);
            if (win == 0) p2[img][c * 25 + pix] = 0.25f * z;
        }
    }
    __syncthreads();

    if (tid < 240) {
        const int c = tid >> 1, h = tid & 1;
        float s0 = 0.f, s1 = 0.f;
        for (int k = 0; k < 200; ++k) {
            float wv = wget_ig(w3e, sg3, sr3, c, 400, h * 200 + k, tg);
            s0 += p2[0][h * 200 + k] * wv;
            s1 += p2[1][h * 200 + k] * wv;
        }
        s0 += __shfl_xor(s0, 1, 64);
        s1 += __shfl_xor(s1, 1, 64);
        if (h == 0) {
            const float bb = b3[c];
            v3[0][c] = sigmoidf(s0 + bb);
            v3[1][c] = sigmoidf(s1 + bb);
        }
    }
    __syncthreads();

    if (tid < 168) {
        const int img = tid / 84, j = tid % 84;
        float a = 0.f;
        for (int k = 0; k < 120; ++k) a += v3[img][k] * fc1w[j * 120 + k];
        v4[img][j] = sigmoidf(a + fc1b[j]);
    }
    __syncthreads();

    if (tid < 20) {
        const int img = tid / 10, j = tid % 10;
        if (img0 + img < nimg) {
            float a = 0.f;
            for (int k = 0; k < 84; ++k) a += v4[img][k] * fc2w[j * 84 + k];
            out[(size_t)(img0 + img) * 10 + j] = a + fc2b[j];
        }
    }
}

extern "C" void kernel_launch(void* const* d_in, const int* in_sizes, int n_in,
                              void* d_out, int out_size, void* d_ws, size_t ws_size,
                              hipStream_t stream) {
    const float* x    = (const float*)d_in[0];
    const float* w1   = (const float*)d_in[1];
    const float* b1   = (const float*)d_in[2];
    const float* sg1  = (const float*)d_in[3];
    const float* w2   = (const float*)d_in[4];
    const float* b2   = (const float*)d_in[5];
    const float* sg2  = (const float*)d_in[6];
    const float* w3   = (const float*)d_in[7];
    const float* b3   = (const float*)d_in[8];
    const float* sg3  = (const float*)d_in[9];
    const float* fc1w = (const float*)d_in[10];
    const float* fc1b = (const float*)d_in[11];
    const float* fc2w = (const float*)d_in[12];
    const float* fc2b = (const float*)d_in[13];
    const int*   sr1  = (const int*)d_in[14];
    const int*   sr2  = (const int*)d_in[15];
    const int*   sr3  = (const int*)d_in[16];
    const int*   trig = (const int*)d_in[17];

    const int nimg = in_sizes[0] / 1024;
    float* out = (float*)d_out;

    const size_t p1off = P1OFF;
    const size_t p2off = p1off + (size_t)nimg * 1176;
    const size_t need_bytes = (p2off + (size_t)nimg * 400) * sizeof(float);

    if (ws_size >= need_bytes) {
        float* ws = (float*)d_ws;
        weff_prep<<<(P1OFF + 255) / 256, 256, 0, stream>>>(
            w1, sg1, sr1, w2, sg2, sr2, w3, sg3, sr3, trig, ws);
        k_conv1<<<(nimg * 98 + THREADS - 1) / THREADS, THREADS, 0, stream>>>(
            x, ws, b1, ws + p1off, nimg);
        k_conv2<<<(nimg * 50 + THREADS - 1) / THREADS, THREADS, 0, stream>>>(
            ws + p1off, ws, b2, ws + p2off, nimg);
        k_tail<<<(nimg + T_IMG - 1) / T_IMG, 128, 0, stream>>>(
            ws + p2off, ws, b3, fc1w, fc1b, fc2w, fc2b, out, nimg);
    } else {
        lenet_fused<<<(nimg + 1) / 2, THREADS, 0, stream>>>(
            x, w1, b1, w2, b2, w3, b3,
            fc1w, fc1b, fc2w, fc2b, sg1, sr1, sg2, sr2, sg3, sr3, trig, out, nimg);
    }
}